// Round 6
// baseline (447.825 us; speedup 1.0000x reference)
//
#include <hip/hip_runtime.h>
#include <hip/hip_bf16.h>

// B=8192, N=M=K=2048, H=10.
// Pipeline (4 launches):
//   1) pre_kernel: fused [col-sum partials] + [row sums] + [X -> Xh,Xl bf16 split]
//   2) nca_update: finish col sums inline, per-cell MLP, write TRANSPOSED bf16
//      split Bth/Btl [M][N]
//   3) 3-term bf16 MFMA GEMM, WAVE-PRIVATE staging, ZERO barriers:
//      each wave owns a 64x64 tile, stages its own A/B into private LDS,
//      guards with per-wave s_waitcnt vmcnt(0). No __syncthreads -> no
//      phase-lock drain stall (the m97-structure 41%-MfmaUtil cap).
//   4) row softmax, one WAVE per row (no LDS, no barriers)

typedef short short8 __attribute__((ext_vector_type(8)));
typedef float floatx4 __attribute__((ext_vector_type(4)));

#define GK 2048
#define NROWS 2048
#define MCOLS 2048
#define NCHUNK 16

__device__ inline unsigned short f2bf_rne(float x) {
  unsigned u = __float_as_uint(x);
  unsigned r = (u + 0x7fffu + ((u >> 16) & 1u)) >> 16;
  return (unsigned short)r;
}
__device__ inline float bf2f(unsigned short h) {
  return __uint_as_float(((unsigned)h) << 16);
}

// ---------------- fused pre-pass --------------------------------------------
#define CS_BLOCKS 128
#define RS_BLOCKS 2048
__global__ __launch_bounds__(256) void pre_kernel(
    const float* __restrict__ X, const float* __restrict__ W,
    unsigned short* __restrict__ Xh, unsigned short* __restrict__ Xl,
    float* __restrict__ part, float* __restrict__ rowS) {
  const int bid = blockIdx.x;
  const int tid = threadIdx.x;

  if (bid < CS_BLOCKS) {
    int chunk = bid >> 3;                 // 0..15
    int j = (bid & 7) * 256 + tid;        // column
    int i0 = chunk * (NROWS / NCHUNK);
    float s = 0.f;
    for (int i = i0; i < i0 + NROWS / NCHUNK; ++i) s += W[(size_t)i * MCOLS + j];
    part[(size_t)chunk * MCOLS + j] = s;
  } else if (bid < CS_BLOCKS + RS_BLOCKS) {
    int row = bid - CS_BLOCKS;
    const float4* p = (const float4*)(W + (size_t)row * MCOLS);
    float4 a = p[tid];
    float4 b = p[tid + 256];
    float v = (a.x + a.y) + (a.z + a.w) + (b.x + b.y) + (b.z + b.w);
    __shared__ float red[256];
    red[tid] = v;
    __syncthreads();
    for (int s = 128; s > 0; s >>= 1) {
      if (tid < s) red[tid] += red[tid + s];
      __syncthreads();
    }
    if (tid == 0) rowS[row] = red[0];
  } else {
    size_t i = (size_t)(bid - CS_BLOCKS - RS_BLOCKS) * 256 + tid;
    float4 v = ((const float4*)X)[i];
    ushort4 h, l;
    h.x = f2bf_rne(v.x); l.x = f2bf_rne(v.x - bf2f(h.x));
    h.y = f2bf_rne(v.y); l.y = f2bf_rne(v.y - bf2f(h.y));
    h.z = f2bf_rne(v.z); l.z = f2bf_rne(v.z - bf2f(h.z));
    h.w = f2bf_rne(v.w); l.w = f2bf_rne(v.w - bf2f(h.w));
    ((ushort4*)Xh)[i] = h;
    ((ushort4*)Xl)[i] = l;
  }
}

// ------- NCA MLP -> new_weight, transposed bf16 split out -------------------
__global__ __launch_bounds__(256) void nca_update_kernel(
    const float* __restrict__ W, const float* __restrict__ part,
    const float* __restrict__ rowS,
    const float* __restrict__ W1, const float* __restrict__ b1,
    const float* __restrict__ W2, const float* __restrict__ b2,
    const float* __restrict__ W3, const float* __restrict__ b3,
    unsigned short* __restrict__ Bth, unsigned short* __restrict__ Btl) {
  __shared__ float sW1[30], sb1[10], sW2[100], sb2[10], sW3[10], sb3;
  __shared__ float sColS[32];
  __shared__ float cred[NCHUNK][33];
  __shared__ unsigned short Th[32][33], Tl[32][33];
  const int tid = threadIdx.x;
  const int i0 = blockIdx.y * 32;
  const int j0 = blockIdx.x * 32;

  if (tid < 30) sW1[tid] = W1[tid];
  if (tid < 10) { sb1[tid] = b1[tid]; sb2[tid] = b2[tid]; sW3[tid] = W3[tid]; }
  if (tid >= 32 && tid < 132) sW2[tid - 32] = W2[tid - 32];
  if (tid == 0) sb3 = b3[0];

  {
    int ch = tid >> 5;
    int jl = tid & 31;
    cred[ch][jl]     = part[(size_t)ch * MCOLS + j0 + jl];
    cred[ch + 8][jl] = part[(size_t)(ch + 8) * MCOLS + j0 + jl];
  }
  __syncthreads();
  if (tid < 32) {
    float s = 0.f;
#pragma unroll
    for (int c = 0; c < NCHUNK; ++c) s += cred[c][tid];
    sColS[tid] = s;
  }
  __syncthreads();

  const int r = tid >> 5;
  const int c = tid & 31;

  float w[4], fwd[4], bwd[4];
#pragma unroll
  for (int cell = 0; cell < 4; ++cell) {
    int il = r + 8 * cell;
    float wv = W[(size_t)(i0 + il) * MCOLS + j0 + c];
    w[cell] = wv;
    fwd[cell] = (sColS[c] - wv) * (1.0f / (float)(NROWS - 1));
    bwd[cell] = (rowS[i0 + il] - wv) * (1.0f / (float)(MCOLS - 1));
  }

  float h1[4][10];
#pragma unroll
  for (int o = 0; o < 10; ++o) {
    float w1a = sW1[o], w1b = sW1[10 + o], w1c = sW1[20 + o], bb = sb1[o];
#pragma unroll
    for (int cell = 0; cell < 4; ++cell) {
      float v = fmaf(w[cell], w1a, fmaf(fwd[cell], w1b, fmaf(bwd[cell], w1c, bb)));
      h1[cell][o] = fmaxf(v, 0.f);
    }
  }
  float u[4] = {sb3, sb3, sb3, sb3};
#pragma unroll
  for (int o = 0; o < 10; ++o) {
    float h2[4];
    float bb = sb2[o];
#pragma unroll
    for (int cell = 0; cell < 4; ++cell) h2[cell] = bb;
#pragma unroll
    for (int p = 0; p < 10; ++p) {
      float wv = sW2[p * 10 + o];
#pragma unroll
      for (int cell = 0; cell < 4; ++cell) h2[cell] = fmaf(h1[cell][p], wv, h2[cell]);
    }
    float w3 = sW3[o];
#pragma unroll
    for (int cell = 0; cell < 4; ++cell) u[cell] = fmaf(fmaxf(h2[cell], 0.f), w3, u[cell]);
  }

#pragma unroll
  for (int cell = 0; cell < 4; ++cell) {
    int il = r + 8 * cell;
    float nw = w[cell] + u[cell];
    unsigned short hb = f2bf_rne(nw);
    Th[il][c] = hb;
    Tl[il][c] = f2bf_rne(nw - bf2f(hb));
  }
  __syncthreads();

#pragma unroll
  for (int cell = 0; cell < 4; ++cell) {
    int jl = r + 8 * cell;
    size_t oidx = (size_t)(j0 + jl) * NROWS + i0 + c;
    Bth[oidx] = Th[c][jl];
    Btl[oidx] = Tl[c][jl];
  }
}

// ---------------- 3-term bf16 MFMA GEMM, wave-private, zero-barrier ---------
// Wave w of the block owns output tile (by*128 + (w>>1)*64, bx*128 + (w&1)*64)
// and stages its own A-band (64 rows) and B-slab (64 cols) into private LDS
// (16KB/wave, 64KB/block). Staging/fragment swizzle identical to R5 (verified):
//   staging lane l -> row16 = l>>2, kchunk = (l&3)^((l>>3)&3)
//   frag slot      = 4*(l&15) + ((l>>4) ^ ((l>>1)&3))
// No __syncthreads anywhere; per-wave s_waitcnt vmcnt(0) guards LDS arrival.
__global__ __launch_bounds__(256) void gemm_kernel(
    const unsigned short* __restrict__ Xh, const unsigned short* __restrict__ Xl,
    const unsigned short* __restrict__ Bth, const unsigned short* __restrict__ Btl,
    float* __restrict__ C) {
  __shared__ short sAh[4][2048];   // [wave][64 rows x 32 k]
  __shared__ short sAl[4][2048];
  __shared__ short sBh[4][2048];
  __shared__ short sBl[4][2048];

  const int tid = threadIdx.x;
  const int lane = tid & 63;
  const int wave = tid >> 6;
  const int wr = wave >> 1;
  const int wc = wave & 1;
  const int fm = lane & 15;
  const int q = lane >> 4;

  const int bx = blockIdx.x;
  const int by = blockIdx.y;

  const unsigned short* A0h = Xh  + (size_t)(by * 128 + wr * 64) * GK;
  const unsigned short* A0l = Xl  + (size_t)(by * 128 + wr * 64) * GK;
  const unsigned short* B0h = Bth + (size_t)(bx * 128 + wc * 64) * GK;
  const unsigned short* B0l = Btl + (size_t)(bx * 128 + wc * 64) * GK;

  const int srow = lane >> 2;                              // 0..15
  const int skof = ((lane & 3) ^ ((lane >> 3) & 3)) * 8;   // swizzled k-chunk
  const int sfrag = 4 * fm + (q ^ ((lane >> 1) & 3));      // frag slot 0..63

  floatx4 acc[4][4];
#pragma unroll
  for (int i = 0; i < 4; ++i)
#pragma unroll
    for (int j = 0; j < 4; ++j) acc[i][j] = (floatx4){0.f, 0.f, 0.f, 0.f};

  for (int k0 = 0; k0 < GK; k0 += 32) {
#pragma unroll
    for (int i = 0; i < 4; ++i) {                 // 16-row blocks of the band
      size_t goff = (size_t)(i * 16 + srow) * GK + k0 + skof;
      int ldsoff = i * 512;                       // shorts
      __builtin_amdgcn_global_load_lds(
          (const __attribute__((address_space(1))) void*)(A0h + goff),
          (__attribute__((address_space(3))) void*)(&sAh[wave][ldsoff]), 16, 0, 0);
      __builtin_amdgcn_global_load_lds(
          (const __attribute__((address_space(1))) void*)(A0l + goff),
          (__attribute__((address_space(3))) void*)(&sAl[wave][ldsoff]), 16, 0, 0);
      __builtin_amdgcn_global_load_lds(
          (const __attribute__((address_space(1))) void*)(B0h + goff),
          (__attribute__((address_space(3))) void*)(&sBh[wave][ldsoff]), 16, 0, 0);
      __builtin_amdgcn_global_load_lds(
          (const __attribute__((address_space(1))) void*)(B0l + goff),
          (__attribute__((address_space(3))) void*)(&sBl[wave][ldsoff]), 16, 0, 0);
    }
    // wait for THIS wave's 16 staging loads only (wave-private counter)
    __builtin_amdgcn_s_waitcnt(0x0F70);  // vmcnt(0), exp/lgkm unconstrained

    short8 ah[4], al[4], bh[4], bl[4];
#pragma unroll
    for (int mi = 0; mi < 4; ++mi) {
      int off = mi * 512 + sfrag * 8;
      ah[mi] = *(const short8*)(&sAh[wave][off]);
      al[mi] = *(const short8*)(&sAl[wave][off]);
    }
#pragma unroll
    for (int ni = 0; ni < 4; ++ni) {
      int off = ni * 512 + sfrag * 8;
      bh[ni] = *(const short8*)(&sBh[wave][off]);
      bl[ni] = *(const short8*)(&sBl[wave][off]);
    }
#pragma unroll
    for (int mi = 0; mi < 4; ++mi)
#pragma unroll
      for (int ni = 0; ni < 4; ++ni) {
        acc[mi][ni] = __builtin_amdgcn_mfma_f32_16x16x32_bf16(ah[mi], bh[ni], acc[mi][ni], 0, 0, 0);
        acc[mi][ni] = __builtin_amdgcn_mfma_f32_16x16x32_bf16(al[mi], bh[ni], acc[mi][ni], 0, 0, 0);
        acc[mi][ni] = __builtin_amdgcn_mfma_f32_16x16x32_bf16(ah[mi], bl[ni], acc[mi][ni], 0, 0, 0);
      }
    // ensure this wave's ds_reads retired before next-iter LDS overwrite
    __builtin_amdgcn_s_waitcnt(0xC07F);  // lgkmcnt(0)
  }

#pragma unroll
  for (int mi = 0; mi < 4; ++mi)
#pragma unroll
    for (int ni = 0; ni < 4; ++ni) {
      int col = bx * 128 + wc * 64 + ni * 16 + fm;
#pragma unroll
      for (int r = 0; r < 4; ++r) {
        int row = by * 128 + wr * 64 + mi * 16 + q * 4 + r;
        C[(size_t)row * 2048 + col] = acc[mi][ni][r];
      }
    }
}

// ---------------- row softmax: one wave per row, no LDS, no barriers --------
__global__ __launch_bounds__(256) void softmax_kernel(float* __restrict__ C) {
  const int lane = threadIdx.x & 63;
  const int wv = threadIdx.x >> 6;
  const int row = blockIdx.x * 4 + wv;
  float4* p = (float4*)(C + (size_t)row * MCOLS);

  float4 v[8];
#pragma unroll
  for (int j = 0; j < 8; ++j) v[j] = p[j * 64 + lane];

  float vmax = -3.4e38f;
#pragma unroll
  for (int j = 0; j < 8; ++j)
    vmax = fmaxf(vmax, fmaxf(fmaxf(v[j].x, v[j].y), fmaxf(v[j].z, v[j].w)));
#pragma unroll
  for (int off = 32; off > 0; off >>= 1)
    vmax = fmaxf(vmax, __shfl_xor(vmax, off));

  float sum = 0.f;
#pragma unroll
  for (int j = 0; j < 8; ++j) {
    v[j].x = __expf(v[j].x - vmax);
    v[j].y = __expf(v[j].y - vmax);
    v[j].z = __expf(v[j].z - vmax);
    v[j].w = __expf(v[j].w - vmax);
    sum += (v[j].x + v[j].y) + (v[j].z + v[j].w);
  }
#pragma unroll
  for (int off = 32; off > 0; off >>= 1)
    sum += __shfl_xor(sum, off);
  float inv = 1.0f / sum;

#pragma unroll
  for (int j = 0; j < 8; ++j) {
    v[j].x *= inv; v[j].y *= inv; v[j].z *= inv; v[j].w *= inv;
    p[j * 64 + lane] = v[j];
  }
}

// ---------------- launcher --------------------------------------------------
extern "C" void kernel_launch(void* const* d_in, const int* in_sizes, int n_in,
                              void* d_out, int out_size, void* d_ws, size_t ws_size,
                              hipStream_t stream) {
  const float* X      = (const float*)d_in[0];
  const float* weight = (const float*)d_in[1];
  const float* W1     = (const float*)d_in[2];
  const float* b1     = (const float*)d_in[3];
  const float* W2     = (const float*)d_in[4];
  const float* b2     = (const float*)d_in[5];
  const float* W3     = (const float*)d_in[6];
  const float* b3     = (const float*)d_in[7];
  float* out = (float*)d_out;

  const int N = 2048, M = 2048;
  const int Bdim = in_sizes[0] / N;   // 8192

  float* rowS = (float*)d_ws;
  float* part = rowS + 2048;
  unsigned short* Xh  = (unsigned short*)(part + NCHUNK * 2048);
  unsigned short* Xl  = Xh + (size_t)Bdim * N;
  unsigned short* Bth = Xl + (size_t)Bdim * N;
  unsigned short* Btl = Bth + (size_t)M * N;

  const int conv_blocks = (Bdim * N) / 4 / 256;  // 16384
  pre_kernel<<<CS_BLOCKS + RS_BLOCKS + conv_blocks, 256, 0, stream>>>(
      X, weight, Xh, Xl, part, rowS);

  nca_update_kernel<<<dim3(M / 32, N / 32), 256, 0, stream>>>(
      weight, part, rowS, W1, b1, W2, b2, W3, b3, Bth, Btl);

  gemm_kernel<<<dim3(M / 128, Bdim / 128), 256, 0, stream>>>(Xh, Xl, Bth, Btl, out);

  softmax_kernel<<<Bdim / 4, 256, 0, stream>>>(out);
}

// Round 7
// 380.015 us; speedup vs baseline: 1.1784x; 1.1784x over previous
//
#include <hip/hip_runtime.h>
#include <hip/hip_bf16.h>

// B=8192, N=M=K=2048, H=10.
// Pipeline (4 launches):
//   1) pre_kernel: fused [col-sum partials] + [row sums] + [X -> Xh,Xl bf16 split]
//   2) nca_update: finish col sums inline, per-cell MLP, write TRANSPOSED bf16
//      split Bth/Btl [M][N]
//   3) 3-term bf16 MFMA GEMM, R5 block-shared staging + XOR swizzle,
//      MFMA shape 32x32x16 (half the instructions of 16x16x32, m119: higher-
//      efficiency pipe).
//   4) row softmax, one WAVE per row (no LDS, no barriers)

typedef short short8 __attribute__((ext_vector_type(8)));
typedef float floatx4 __attribute__((ext_vector_type(4)));
typedef float floatx16 __attribute__((ext_vector_type(16)));

#define GK 2048
#define NROWS 2048
#define MCOLS 2048
#define NCHUNK 16

__device__ inline unsigned short f2bf_rne(float x) {
  unsigned u = __float_as_uint(x);
  unsigned r = (u + 0x7fffu + ((u >> 16) & 1u)) >> 16;
  return (unsigned short)r;
}
__device__ inline float bf2f(unsigned short h) {
  return __uint_as_float(((unsigned)h) << 16);
}

// ---------------- fused pre-pass --------------------------------------------
#define CS_BLOCKS 128
#define RS_BLOCKS 2048
__global__ __launch_bounds__(256) void pre_kernel(
    const float* __restrict__ X, const float* __restrict__ W,
    unsigned short* __restrict__ Xh, unsigned short* __restrict__ Xl,
    float* __restrict__ part, float* __restrict__ rowS) {
  const int bid = blockIdx.x;
  const int tid = threadIdx.x;

  if (bid < CS_BLOCKS) {
    int chunk = bid >> 3;                 // 0..15
    int j = (bid & 7) * 256 + tid;        // column
    int i0 = chunk * (NROWS / NCHUNK);
    float s = 0.f;
    for (int i = i0; i < i0 + NROWS / NCHUNK; ++i) s += W[(size_t)i * MCOLS + j];
    part[(size_t)chunk * MCOLS + j] = s;
  } else if (bid < CS_BLOCKS + RS_BLOCKS) {
    int row = bid - CS_BLOCKS;
    const float4* p = (const float4*)(W + (size_t)row * MCOLS);
    float4 a = p[tid];
    float4 b = p[tid + 256];
    float v = (a.x + a.y) + (a.z + a.w) + (b.x + b.y) + (b.z + b.w);
    __shared__ float red[256];
    red[tid] = v;
    __syncthreads();
    for (int s = 128; s > 0; s >>= 1) {
      if (tid < s) red[tid] += red[tid + s];
      __syncthreads();
    }
    if (tid == 0) rowS[row] = red[0];
  } else {
    size_t i = (size_t)(bid - CS_BLOCKS - RS_BLOCKS) * 256 + tid;
    float4 v = ((const float4*)X)[i];
    ushort4 h, l;
    h.x = f2bf_rne(v.x); l.x = f2bf_rne(v.x - bf2f(h.x));
    h.y = f2bf_rne(v.y); l.y = f2bf_rne(v.y - bf2f(h.y));
    h.z = f2bf_rne(v.z); l.z = f2bf_rne(v.z - bf2f(h.z));
    h.w = f2bf_rne(v.w); l.w = f2bf_rne(v.w - bf2f(h.w));
    ((ushort4*)Xh)[i] = h;
    ((ushort4*)Xl)[i] = l;
  }
}

// ------- NCA MLP -> new_weight, transposed bf16 split out -------------------
__global__ __launch_bounds__(256) void nca_update_kernel(
    const float* __restrict__ W, const float* __restrict__ part,
    const float* __restrict__ rowS,
    const float* __restrict__ W1, const float* __restrict__ b1,
    const float* __restrict__ W2, const float* __restrict__ b2,
    const float* __restrict__ W3, const float* __restrict__ b3,
    unsigned short* __restrict__ Bth, unsigned short* __restrict__ Btl) {
  __shared__ float sW1[30], sb1[10], sW2[100], sb2[10], sW3[10], sb3;
  __shared__ float sColS[32];
  __shared__ float cred[NCHUNK][33];
  __shared__ unsigned short Th[32][33], Tl[32][33];
  const int tid = threadIdx.x;
  const int i0 = blockIdx.y * 32;
  const int j0 = blockIdx.x * 32;

  if (tid < 30) sW1[tid] = W1[tid];
  if (tid < 10) { sb1[tid] = b1[tid]; sb2[tid] = b2[tid]; sW3[tid] = W3[tid]; }
  if (tid >= 32 && tid < 132) sW2[tid - 32] = W2[tid - 32];
  if (tid == 0) sb3 = b3[0];

  {
    int ch = tid >> 5;
    int jl = tid & 31;
    cred[ch][jl]     = part[(size_t)ch * MCOLS + j0 + jl];
    cred[ch + 8][jl] = part[(size_t)(ch + 8) * MCOLS + j0 + jl];
  }
  __syncthreads();
  if (tid < 32) {
    float s = 0.f;
#pragma unroll
    for (int c = 0; c < NCHUNK; ++c) s += cred[c][tid];
    sColS[tid] = s;
  }
  __syncthreads();

  const int r = tid >> 5;
  const int c = tid & 31;

  float w[4], fwd[4], bwd[4];
#pragma unroll
  for (int cell = 0; cell < 4; ++cell) {
    int il = r + 8 * cell;
    float wv = W[(size_t)(i0 + il) * MCOLS + j0 + c];
    w[cell] = wv;
    fwd[cell] = (sColS[c] - wv) * (1.0f / (float)(NROWS - 1));
    bwd[cell] = (rowS[i0 + il] - wv) * (1.0f / (float)(MCOLS - 1));
  }

  float h1[4][10];
#pragma unroll
  for (int o = 0; o < 10; ++o) {
    float w1a = sW1[o], w1b = sW1[10 + o], w1c = sW1[20 + o], bb = sb1[o];
#pragma unroll
    for (int cell = 0; cell < 4; ++cell) {
      float v = fmaf(w[cell], w1a, fmaf(fwd[cell], w1b, fmaf(bwd[cell], w1c, bb)));
      h1[cell][o] = fmaxf(v, 0.f);
    }
  }
  float u[4] = {sb3, sb3, sb3, sb3};
#pragma unroll
  for (int o = 0; o < 10; ++o) {
    float h2[4];
    float bb = sb2[o];
#pragma unroll
    for (int cell = 0; cell < 4; ++cell) h2[cell] = bb;
#pragma unroll
    for (int p = 0; p < 10; ++p) {
      float wv = sW2[p * 10 + o];
#pragma unroll
      for (int cell = 0; cell < 4; ++cell) h2[cell] = fmaf(h1[cell][p], wv, h2[cell]);
    }
    float w3 = sW3[o];
#pragma unroll
    for (int cell = 0; cell < 4; ++cell) u[cell] = fmaf(fmaxf(h2[cell], 0.f), w3, u[cell]);
  }

#pragma unroll
  for (int cell = 0; cell < 4; ++cell) {
    int il = r + 8 * cell;
    float nw = w[cell] + u[cell];
    unsigned short hb = f2bf_rne(nw);
    Th[il][c] = hb;
    Tl[il][c] = f2bf_rne(nw - bf2f(hb));
  }
  __syncthreads();

  // transposed write, ushort2-vectorized: out[j][i], 2 consecutive i/thread
  {
    int r2 = tid >> 4;          // 0..15
    int ic = (tid & 15) * 2;    // 0..30
#pragma unroll
    for (int half = 0; half < 2; ++half) {
      int jl = r2 + 16 * half;
      ushort2 vh, vl;
      vh.x = Th[ic][jl];     vh.y = Th[ic + 1][jl];
      vl.x = Tl[ic][jl];     vl.y = Tl[ic + 1][jl];
      size_t oidx = (size_t)(j0 + jl) * NROWS + i0 + ic;
      *(ushort2*)(&Bth[oidx]) = vh;
      *(ushort2*)(&Btl[oidx]) = vl;
    }
  }
}

// ---------------- 3-term bf16 MFMA GEMM (R5 staging, 32x32x16 MFMA) ---------
// Staging (per 16-row block R): lane l fetches global
//   row = R*16 + (l>>2), kchunk = (l&3) ^ ((l>>3)&3)   (8 bf16 = 16B)
// LDS slot s in block R holds (row = s>>2, kchunk = (s&3)^((s>>3)&3));
// to read row r, chunk c: slot = 4r + (c ^ ((r>>1)&3))  -> 2-way max (free).
// MFMA 32x32x16: A-frag lane l = A[m=l&31][k=(l>>5)*8+j]; C/D col=lane&31,
// row=(reg&3)+8*(reg>>2)+4*(lane>>5)  [m74/m101-verified].
__global__ __launch_bounds__(256) void gemm_kernel(
    const unsigned short* __restrict__ Xh, const unsigned short* __restrict__ Xl,
    const unsigned short* __restrict__ Bth, const unsigned short* __restrict__ Btl,
    float* __restrict__ C) {
  __shared__ short sAh[128 * 32];
  __shared__ short sAl[128 * 32];
  __shared__ short sBh[128 * 32];
  __shared__ short sBl[128 * 32];

  const int tid = threadIdx.x;
  const int lane = tid & 63;
  const int wave = tid >> 6;
  const int wr = wave >> 1;    // 64-row quadrant
  const int wc = wave & 1;     // 64-col quadrant

  const int bx = blockIdx.x;
  const int by = blockIdx.y;

  const unsigned short* A0h = Xh + (size_t)(by * 128) * GK;
  const unsigned short* A0l = Xl + (size_t)(by * 128) * GK;
  const unsigned short* B0h = Bth + (size_t)(bx * 128) * GK;
  const unsigned short* B0l = Btl + (size_t)(bx * 128) * GK;

  // staging address components (per lane, loop-invariant)
  const int srow = lane >> 2;                             // 0..15
  const int skof = ((lane & 3) ^ ((lane >> 3) & 3)) * 8;  // swizzled k-chunk

  // fragment read components (per lane, loop-invariant)
  const int fr = lane & 15;            // row within 16-row block
  const int fhalf = (lane >> 4) & 1;   // which 16-row block of the 32-row tile
  const int fkg = lane >> 5;           // k-group (0/1) within K=16 step
  const int fsw = (lane >> 1) & 3;     // swizzle term ((r>>1)&3) == bits1-2 of lane

  floatx16 acc[2][2];
#pragma unroll
  for (int i = 0; i < 2; ++i)
#pragma unroll
    for (int j = 0; j < 2; ++j)
#pragma unroll
      for (int e = 0; e < 16; ++e) acc[i][j][e] = 0.f;

  for (int k0 = 0; k0 < GK; k0 += 32) {
#pragma unroll
    for (int r = 0; r < 2; ++r) {
      int R = wave * 2 + r;                       // 16-row block 0..7
      size_t goff = (size_t)(R * 16 + srow) * GK + k0 + skof;
      int ldsoff = R * 512;                       // shorts (1KB per block)
      __builtin_amdgcn_global_load_lds(
          (const __attribute__((address_space(1))) void*)(A0h + goff),
          (__attribute__((address_space(3))) void*)(sAh + ldsoff), 16, 0, 0);
      __builtin_amdgcn_global_load_lds(
          (const __attribute__((address_space(1))) void*)(A0l + goff),
          (__attribute__((address_space(3))) void*)(sAl + ldsoff), 16, 0, 0);
      __builtin_amdgcn_global_load_lds(
          (const __attribute__((address_space(1))) void*)(B0h + goff),
          (__attribute__((address_space(3))) void*)(sBh + ldsoff), 16, 0, 0);
      __builtin_amdgcn_global_load_lds(
          (const __attribute__((address_space(1))) void*)(B0l + goff),
          (__attribute__((address_space(3))) void*)(sBl + ldsoff), 16, 0, 0);
    }
    __syncthreads();

    short8 ah[2][2], al[2][2], bh[2][2], bl[2][2];  // [tile][ks]
#pragma unroll
    for (int mi = 0; mi < 2; ++mi)
#pragma unroll
      for (int ks = 0; ks < 2; ++ks) {
        int R = wr * 4 + mi * 2 + fhalf;
        int slot = 4 * fr + ((ks * 2 + fkg) ^ fsw);
        int off = R * 512 + slot * 8;
        ah[mi][ks] = *(const short8*)(sAh + off);
        al[mi][ks] = *(const short8*)(sAl + off);
      }
#pragma unroll
    for (int ni = 0; ni < 2; ++ni)
#pragma unroll
      for (int ks = 0; ks < 2; ++ks) {
        int R = wc * 4 + ni * 2 + fhalf;
        int slot = 4 * fr + ((ks * 2 + fkg) ^ fsw);
        int off = R * 512 + slot * 8;
        bh[ni][ks] = *(const short8*)(sBh + off);
        bl[ni][ks] = *(const short8*)(sBl + off);
      }
#pragma unroll
    for (int mi = 0; mi < 2; ++mi)
#pragma unroll
      for (int ni = 0; ni < 2; ++ni)
#pragma unroll
        for (int ks = 0; ks < 2; ++ks) {
          acc[mi][ni] = __builtin_amdgcn_mfma_f32_32x32x16_bf16(ah[mi][ks], bh[ni][ks], acc[mi][ni], 0, 0, 0);
          acc[mi][ni] = __builtin_amdgcn_mfma_f32_32x32x16_bf16(al[mi][ks], bh[ni][ks], acc[mi][ni], 0, 0, 0);
          acc[mi][ni] = __builtin_amdgcn_mfma_f32_32x32x16_bf16(ah[mi][ks], bl[ni][ks], acc[mi][ni], 0, 0, 0);
        }
    __syncthreads();
  }

  // epilogue: 32x32 C/D layout col=lane&31, row=(reg&3)+8*(reg>>2)+4*(lane>>5)
  const int ecol = lane & 31;
  const int erow = 4 * (lane >> 5);
#pragma unroll
  for (int mi = 0; mi < 2; ++mi)
#pragma unroll
    for (int ni = 0; ni < 2; ++ni) {
      int col = bx * 128 + wc * 64 + ni * 32 + ecol;
#pragma unroll
      for (int reg = 0; reg < 16; ++reg) {
        int row = by * 128 + wr * 64 + mi * 32 + (reg & 3) + 8 * (reg >> 2) + erow;
        C[(size_t)row * 2048 + col] = acc[mi][ni][reg];
      }
    }
}

// ---------------- row softmax: one wave per row, no LDS, no barriers --------
__global__ __launch_bounds__(256) void softmax_kernel(float* __restrict__ C) {
  const int lane = threadIdx.x & 63;
  const int wv = threadIdx.x >> 6;
  const int row = blockIdx.x * 4 + wv;
  float4* p = (float4*)(C + (size_t)row * MCOLS);

  float4 v[8];
#pragma unroll
  for (int j = 0; j < 8; ++j) v[j] = p[j * 64 + lane];

  float vmax = -3.4e38f;
#pragma unroll
  for (int j = 0; j < 8; ++j)
    vmax = fmaxf(vmax, fmaxf(fmaxf(v[j].x, v[j].y), fmaxf(v[j].z, v[j].w)));
#pragma unroll
  for (int off = 32; off > 0; off >>= 1)
    vmax = fmaxf(vmax, __shfl_xor(vmax, off));

  float sum = 0.f;
#pragma unroll
  for (int j = 0; j < 8; ++j) {
    v[j].x = __expf(v[j].x - vmax);
    v[j].y = __expf(v[j].y - vmax);
    v[j].z = __expf(v[j].z - vmax);
    v[j].w = __expf(v[j].w - vmax);
    sum += (v[j].x + v[j].y) + (v[j].z + v[j].w);
  }
#pragma unroll
  for (int off = 32; off > 0; off >>= 1)
    sum += __shfl_xor(sum, off);
  float inv = 1.0f / sum;

#pragma unroll
  for (int j = 0; j < 8; ++j) {
    v[j].x *= inv; v[j].y *= inv; v[j].z *= inv; v[j].w *= inv;
    p[j * 64 + lane] = v[j];
  }
}

// ---------------- launcher --------------------------------------------------
extern "C" void kernel_launch(void* const* d_in, const int* in_sizes, int n_in,
                              void* d_out, int out_size, void* d_ws, size_t ws_size,
                              hipStream_t stream) {
  const float* X      = (const float*)d_in[0];
  const float* weight = (const float*)d_in[1];
  const float* W1     = (const float*)d_in[2];
  const float* b1     = (const float*)d_in[3];
  const float* W2     = (const float*)d_in[4];
  const float* b2     = (const float*)d_in[5];
  const float* W3     = (const float*)d_in[6];
  const float* b3     = (const float*)d_in[7];
  float* out = (float*)d_out;

  const int N = 2048, M = 2048;
  const int Bdim = in_sizes[0] / N;   // 8192

  float* rowS = (float*)d_ws;
  float* part = rowS + 2048;
  unsigned short* Xh  = (unsigned short*)(part + NCHUNK * 2048);
  unsigned short* Xl  = Xh + (size_t)Bdim * N;
  unsigned short* Bth = Xl + (size_t)Bdim * N;
  unsigned short* Btl = Bth + (size_t)M * N;

  const int conv_blocks = (Bdim * N) / 4 / 256;  // 16384
  pre_kernel<<<CS_BLOCKS + RS_BLOCKS + conv_blocks, 256, 0, stream>>>(
      X, weight, Xh, Xl, part, rowS);

  nca_update_kernel<<<dim3(M / 32, N / 32), 256, 0, stream>>>(
      weight, part, rowS, W1, b1, W2, b2, W3, b3, Bth, Btl);

  gemm_kernel<<<dim3(M / 128, Bdim / 128), 256, 0, stream>>>(Xh, Xl, Bth, Btl, out);

  softmax_kernel<<<Bdim / 4, 256, 0, stream>>>(out);
}